// Round 15
// baseline (72.899 us; speedup 1.0000x reference)
//
#include <hip/hip_runtime.h>

// GrCNetConvOnly via MATRIX CORES. B=16384, D=400, C=50.
// R12 proved the VALU path's floor (~43us, VALUBusy 65%, pk_fma ~4cyc = f32 rate).
// MfmaUtil was 0.0 all along. Restructure:
//   stage1: S^T[c,b] = mfma_f32_16x16x32_f16(A=W[16c x K], B=X[K x 16b]) per d,
//           K slots 0..3 = (wa,wb,wc,cb) x (h,r,t,1) -- bias folded into K.
//           Only q=0,e<4 slots used => layout-robust.
//   stage1.5: relu + cvt_pkrtz pack (the only per-element VALU: ~1.5 op/elem).
//   stage2: out-tile = mfma(A=S_relu[16b x 32k], B=fcwB[32k x 16n-replicated]),
//           k=(c,d-pair) enumerated identically on A and B sides (symmetric
//           CDNA A/B layout => any HW k-order gives the same dot product).
//   Stage1 D (m89-verified layout) feeds stage2 A in-register: b = lane&15 both.
// Wave = 1 b-tile(16) x 100 d's; block = 8 waves = 2 b-tiles x 4 d-groups; 512 blocks.
// fcw pre-permuted to LDS as f16 frags (51.2KB): one broadcast ds_read_b128 per
// (c-tile, d-pair). D2 cols all identical; rows = 16 b's -> tiny epilogue reduce.

typedef _Float16 f16x8 __attribute__((ext_vector_type(8)));
typedef float    f32x4 __attribute__((ext_vector_type(4)));

constexpr int D = 400;
constexpr int C = 50;

static __device__ __forceinline__ unsigned pkrtz_u(float lo, float hi) {
    return __builtin_bit_cast(unsigned, __builtin_amdgcn_cvt_pkrtz(lo, hi));
}

__global__ __attribute__((amdgpu_flat_work_group_size(512, 512), amdgpu_waves_per_eu(2, 4)))
void grcnet_mfma(
    const float* __restrict__ entity_emb,
    const float* __restrict__ relation_emb,
    const float* __restrict__ conv_w,       // (C,1,1,3)
    const float* __restrict__ conv_b,       // (C)
    const float* __restrict__ fc_w,         // (C*D) c-major
    const float* __restrict__ fc_b,         // (1)
    const int*   __restrict__ batch_inputs, // (B,3)
    float* __restrict__ out,                // (B)
    int nB)
{
    // fcwB[t][p][q] = 16B frag dword j2: pk(fcw[16t+4q+2(j2&1), 2p+(j2>>1)], fcw[..+1, ..])
    __shared__ __align__(16) unsigned fcwB[4 * 200 * 4 * 4];   // 51200 B
    __shared__ float partials[2][4][16];                        // [b-tile][d-group][b]

    const int tid  = threadIdx.x;
    const int lane = tid & 63;
    const int wv   = tid >> 6;             // 0..7
    const int btl  = wv & 1;               // b-tile within block
    const int dg   = wv >> 1;              // d-group 0..3 (100 d's each)
    const int bq   = blockIdx.x * 32;
    if (bq >= nB) return;

    // ---- stage fcw -> permuted f16 frags in LDS (12800 dwords, 25/thread) ----
    #pragma unroll 1
    for (int it = 0; it < 25; ++it) {
        const int n  = tid + 512 * it;          // = ((t*200+p)*4+q)*4 + j2
        const int t  = n / 3200;
        const int r  = n - t * 3200;
        const int p  = r >> 4;
        const int q  = (r >> 2) & 3;
        const int j2 = r & 3;
        const int c_lo = 16 * t + 4 * q + 2 * (j2 & 1);
        const int d    = 2 * p + (j2 >> 1);
        const float flo = (c_lo     < C) ? fc_w[c_lo * D + d]       : 0.f;
        const float fhi = (c_lo + 1 < C) ? fc_w[(c_lo + 1) * D + d] : 0.f;
        fcwB[n] = pkrtz_u(flo, fhi);
    }

    // ---- A1 frags (W): lane q=0 holds k=0..3 = (wa,wb,wc,cb) for c = 16t + (lane&15) ----
    #define MKA1(T)                                                               \
        f16x8 A1_##T;                                                             \
        {                                                                         \
            const int c   = 16 * (T) + (lane & 15);                               \
            const int cc  = c < C ? c : C - 1;                                    \
            const bool ok = (lane < 16) && (c < C);                               \
            float wa = conv_w[3 * cc + 0], wb = conv_w[3 * cc + 1];               \
            float wc = conv_w[3 * cc + 2], cb = conv_b[cc];                       \
            if (!ok) { wa = 0.f; wb = 0.f; wc = 0.f; cb = 0.f; }                  \
            uint4 u; u.x = pkrtz_u(wa, wb); u.y = pkrtz_u(wc, cb);                \
            u.z = 0u; u.w = 0u;                                                   \
            A1_##T = __builtin_bit_cast(f16x8, u);                                \
        }
    MKA1(0) MKA1(1) MKA1(2) MKA1(3)
    #undef MKA1

    // ---- per-lane row pointers for b = lane&15 (lanes>=16 are duplicates) ----
    const int bidx = bq + 16 * btl + (lane & 15);
    const int* bi  = batch_inputs + 3 * bidx;
    const float* hp = entity_emb   + (size_t)bi[0] * D + dg * 100;
    const float* rp = relation_emb + (size_t)bi[1] * D + dg * 100;
    const float* tp = entity_emb   + (size_t)bi[2] * D + dg * 100;

    __syncthreads();                        // fcwB ready

    const unsigned sel = (lane < 16) ? 0xffffffffu : 0u;  // zero B1 for k-blocks q>0
    const int pbase = dg * 50;
    const unsigned q4 = (unsigned)(lane >> 4);
    const uint4* Fb = (const uint4*)fcwB;

    f32x4 D2 = {0.f, 0.f, 0.f, 0.f};
    const f32x4 Z4 = {0.f, 0.f, 0.f, 0.f};

    #pragma unroll 5
    for (int pl = 0; pl < 50; ++pl) {
        // X loads: float2 over d-pair (lanes>=16 load duplicates; masked to 0 after pack)
        const float2 hv = *(const float2*)(hp + 2 * pl);
        const float2 rv = *(const float2*)(rp + 2 * pl);
        const float2 tv = *(const float2*)(tp + 2 * pl);
        uint4 u0, u1;
        u0.x = pkrtz_u(hv.x, rv.x) & sel;  u0.y = pkrtz_u(tv.x, 1.0f) & sel;
        u0.z = 0u; u0.w = 0u;
        u1.x = pkrtz_u(hv.y, rv.y) & sel;  u1.y = pkrtz_u(tv.y, 1.0f) & sel;
        u1.z = 0u; u1.w = 0u;
        const f16x8 B1a = __builtin_bit_cast(f16x8, u0);
        const f16x8 B1b = __builtin_bit_cast(f16x8, u1);

        const int pg = pbase + pl;

        #define TSTEP(T)                                                          \
        {                                                                         \
            const uint4 F = Fb[(((T) * 200 + pg) << 2) | q4];                     \
            f32x4 s0 = __builtin_amdgcn_mfma_f32_16x16x32_f16(A1_##T, B1a, Z4, 0, 0, 0); \
            f32x4 s1 = __builtin_amdgcn_mfma_f32_16x16x32_f16(A1_##T, B1b, Z4, 0, 0, 0); \
            uint4 a2;                                                             \
            a2.x = pkrtz_u(fmaxf(s0[0], 0.f), fmaxf(s0[1], 0.f));                 \
            a2.y = pkrtz_u(fmaxf(s0[2], 0.f), fmaxf(s0[3], 0.f));                 \
            a2.z = pkrtz_u(fmaxf(s1[0], 0.f), fmaxf(s1[1], 0.f));                 \
            a2.w = pkrtz_u(fmaxf(s1[2], 0.f), fmaxf(s1[3], 0.f));                 \
            D2 = __builtin_amdgcn_mfma_f32_16x16x32_f16(                          \
                     __builtin_bit_cast(f16x8, a2),                               \
                     __builtin_bit_cast(f16x8, F), D2, 0, 0, 0);                  \
        }
        TSTEP(0) TSTEP(1) TSTEP(2) TSTEP(3)
        #undef TSTEP
    }

    // ---- epilogue: D2 rows = 16 b's (cols identical). col==0 lanes write partials ----
    if ((lane & 15) == 0) {
        const int q = lane >> 4;
        partials[btl][dg][4 * q + 0] = D2[0];
        partials[btl][dg][4 * q + 1] = D2[1];
        partials[btl][dg][4 * q + 2] = D2[2];
        partials[btl][dg][4 * q + 3] = D2[3];
    }
    __syncthreads();

    if (tid < 32) {
        const int bt = tid >> 4, b = tid & 15;
        const int bo = bq + 16 * bt + b;
        if (bo < nB)
            out[bo] = partials[bt][0][b] + partials[bt][1][b]
                    + partials[bt][2][b] + partials[bt][3][b] + fc_b[0];
    }
}

extern "C" void kernel_launch(void* const* d_in, const int* in_sizes, int n_in,
                              void* d_out, int out_size, void* d_ws, size_t ws_size,
                              hipStream_t stream) {
    const float* entity_emb   = (const float*)d_in[0];
    const float* relation_emb = (const float*)d_in[1];
    const float* conv_w       = (const float*)d_in[2];
    const float* conv_b       = (const float*)d_in[3];
    const float* fc_w         = (const float*)d_in[4];
    const float* fc_b         = (const float*)d_in[5];
    const int*   batch_inputs = (const int*)d_in[6];
    float* out = (float*)d_out;

    const int nB = in_sizes[6] / 3;          // 16384
    const int blocks = (nB + 31) / 32;       // 512
    grcnet_mfma<<<blocks, 512, 0, stream>>>(
        entity_emb, relation_emb, conv_w, conv_b, fc_w, fc_b, batch_inputs, out, nB);
}

// Round 16
// 61.810 us; speedup vs baseline: 1.1794x; 1.1794x over previous
//
#include <hip/hip_runtime.h>

// GrCNetConvOnly, MFMA stage-1 + dot2 stage-2. B=16384, D=400, C=50.
// R15 (MFMA both stages) passed -> fragment layouts HW-verified, but 51.2KB LDS +
// serial D2 chain + scattered staging made it slow. R16 keeps verified stage-1:
//   S[c, b] = mfma_f32_16x16x32_f16(A=W[16c x K4], B=X[K4 x 16b]) per d
//   (K slots = (wa,wb,wc,cb) x (h,r,t,1); bias folded; lanes>=16 / c>=50 zeroed)
// and replaces stage-2 with v_dot2_f32_f16 against compact fc LDS:
//   fc2[c][p] = pk(fcw[c][2p], fcw[c][2p+1])  (40,000 B; broadcast b32 reads,
//   16-lane groups share one address -> conflict-free; offsets compile-time).
// Lane owns (b = lane&15, c = 16T+4(lane>>4)+r) -> pk(relu s_d0, relu s_d1) dots
// with fc2[c][p] into 4 independent f32 accs. Cross-q reduce = 2 shfl_xor.
// T3 (c=48..63): only r=0,1 real; LDS addr drops the q-term (valid row, x0 = 0).
// Block = 8 waves = 2 b-tiles x 4 d-groups; 512 blocks; LDS ~40.5KB -> 3 blocks/CU.

typedef _Float16 f16x8 __attribute__((ext_vector_type(8)));
typedef _Float16 h2    __attribute__((ext_vector_type(2)));
typedef float    f32x4 __attribute__((ext_vector_type(4)));

constexpr int D = 400;
constexpr int C = 50;

static __device__ __forceinline__ unsigned pkrtz_u(float lo, float hi) {
    return __builtin_bit_cast(unsigned, __builtin_amdgcn_cvt_pkrtz(lo, hi));
}
static __device__ __forceinline__ float dot2(unsigned a, unsigned b, float c) {
    return __builtin_amdgcn_fdot2(__builtin_bit_cast(h2, a),
                                  __builtin_bit_cast(h2, b), c, false);
}

__global__ __attribute__((amdgpu_flat_work_group_size(512, 512), amdgpu_waves_per_eu(2, 8)))
void grcnet_mfma2(
    const float* __restrict__ entity_emb,
    const float* __restrict__ relation_emb,
    const float* __restrict__ conv_w,       // (C,1,1,3)
    const float* __restrict__ conv_b,       // (C)
    const float* __restrict__ fc_w,         // (C*D) c-major
    const float* __restrict__ fc_b,         // (1)
    const int*   __restrict__ batch_inputs, // (B,3)
    float* __restrict__ out,                // (B)
    int nB)
{
    __shared__ unsigned fc2[C * 200];       // 40,000 B: [c*200+p] = pk(f[c][2p], f[c][2p+1])
    __shared__ float partials[2][4][16];    // [b-tile][d-group][b]

    const int tid  = threadIdx.x;
    const int lane = tid & 63;
    const int wv   = tid >> 6;              // 0..7
    const int btl  = wv & 1;                // b-tile in block
    const int dg   = wv >> 1;               // d-group 0..3 (100 d's each)
    const int bq   = blockIdx.x * 32;
    if (bq >= nB) return;

    // ---- stage fc2 (coalesced float2 reads, 1 pkrtz + 1 b32 write each) ----
    for (int k = tid; k < C * 200; k += 512) {
        const int c = k / 200;
        const int p = k - c * 200;
        const float2 v = *(const float2*)(fc_w + c * D + 2 * p);
        fc2[k] = pkrtz_u(v.x, v.y);
    }

    // ---- A1 frags (verified in R15): lanes<16 hold k=0..3 = (wa,wb,wc,cb) ----
    f16x8 A1[4];
    #pragma unroll
    for (int T = 0; T < 4; ++T) {
        const int  c  = 16 * T + (lane & 15);
        const int  cc = c < C ? c : C - 1;
        const bool ok = (lane < 16) && (c < C);
        float wa = conv_w[3*cc+0], wb = conv_w[3*cc+1];
        float wc = conv_w[3*cc+2], cb = conv_b[cc];
        if (!ok) { wa = 0.f; wb = 0.f; wc = 0.f; cb = 0.f; }
        uint4 u; u.x = pkrtz_u(wa, wb); u.y = pkrtz_u(wc, cb); u.z = 0u; u.w = 0u;
        A1[T] = __builtin_bit_cast(f16x8, u);
    }

    // ---- per-lane row pointers for b = lane&15 (lanes>=16 duplicate, L1-coalesced) ----
    const int bidx = bq + 16 * btl + (lane & 15);
    const int* bi  = batch_inputs + 3 * bidx;
    const float* hp = entity_emb   + (size_t)bi[0] * D + dg * 100;
    const float* rp = relation_emb + (size_t)bi[1] * D + dg * 100;
    const float* tp = entity_emb   + (size_t)bi[2] * D + dg * 100;

    __syncthreads();                        // fc2 ready

    const unsigned sel = (lane < 16) ? 0xffffffffu : 0u;
    const int q4 = lane >> 4;
    // fc2 byte addr = (16T+r)*800 [imm] + q4*3200 + dg*200 + pl*4
    const char* fcB  = (const char*)fc2 + q4 * 3200 + dg * 200;  // T0..2 base
    const char* fcBz = (const char*)fc2 + dg * 200;              // T3 base (q-term dropped)

    float acc0 = 0.f, acc1 = 0.f, acc2 = 0.f, acc3 = 0.f;
    const f32x4 Z4 = {0.f, 0.f, 0.f, 0.f};

    #pragma unroll 2
    for (int pl = 0; pl < 50; ++pl) {
        const float2 hv = *(const float2*)(hp + 2 * pl);
        const float2 rv = *(const float2*)(rp + 2 * pl);
        const float2 tv = *(const float2*)(tp + 2 * pl);
        uint4 u0, u1;
        u0.x = pkrtz_u(hv.x, rv.x) & sel;  u0.y = pkrtz_u(tv.x, 1.0f) & sel;
        u0.z = 0u; u0.w = 0u;
        u1.x = pkrtz_u(hv.y, rv.y) & sel;  u1.y = pkrtz_u(tv.y, 1.0f) & sel;
        u1.z = 0u; u1.w = 0u;
        const f16x8 B1a = __builtin_bit_cast(f16x8, u0);
        const f16x8 B1b = __builtin_bit_cast(f16x8, u1);

        const int plo = 4 * pl;

        #pragma unroll
        for (int T = 0; T < 3; ++T) {
            const f32x4 s0 = __builtin_amdgcn_mfma_f32_16x16x32_f16(A1[T], B1a, Z4, 0, 0, 0);
            const f32x4 s1 = __builtin_amdgcn_mfma_f32_16x16x32_f16(A1[T], B1b, Z4, 0, 0, 0);
            const unsigned sp0 = pkrtz_u(fmaxf(s0[0], 0.f), fmaxf(s1[0], 0.f));
            const unsigned sp1 = pkrtz_u(fmaxf(s0[1], 0.f), fmaxf(s1[1], 0.f));
            const unsigned sp2 = pkrtz_u(fmaxf(s0[2], 0.f), fmaxf(s1[2], 0.f));
            const unsigned sp3 = pkrtz_u(fmaxf(s0[3], 0.f), fmaxf(s1[3], 0.f));
            const unsigned f0 = *(const unsigned*)(fcB + plo + (16*T + 0) * 800);
            const unsigned f1 = *(const unsigned*)(fcB + plo + (16*T + 1) * 800);
            const unsigned f2 = *(const unsigned*)(fcB + plo + (16*T + 2) * 800);
            const unsigned f3 = *(const unsigned*)(fcB + plo + (16*T + 3) * 800);
            acc0 = dot2(sp0, f0, acc0);
            acc1 = dot2(sp1, f1, acc1);
            acc2 = dot2(sp2, f2, acc2);
            acc3 = dot2(sp3, f3, acc3);
        }
        {   // T = 3: c = 48 + 4*q4 + r; only q4==0, r<2 real. Reads use q-less base
            // (rows 48+r valid for all lanes; lanes with c>=50 have sp==0 -> adds 0).
            const f32x4 s0 = __builtin_amdgcn_mfma_f32_16x16x32_f16(A1[3], B1a, Z4, 0, 0, 0);
            const f32x4 s1 = __builtin_amdgcn_mfma_f32_16x16x32_f16(A1[3], B1b, Z4, 0, 0, 0);
            const unsigned sp0 = pkrtz_u(fmaxf(s0[0], 0.f), fmaxf(s1[0], 0.f));
            const unsigned sp1 = pkrtz_u(fmaxf(s0[1], 0.f), fmaxf(s1[1], 0.f));
            const unsigned f0 = *(const unsigned*)(fcBz + plo + 48 * 800);
            const unsigned f1 = *(const unsigned*)(fcBz + plo + 49 * 800);
            acc0 = dot2(sp0, f0, acc0);
            acc1 = dot2(sp1, f1, acc1);
        }
    }

    // ---- reduce over q-groups (lanes b, b+16, b+32, b+48 hold same-b partials) ----
    float v = (acc0 + acc1) + (acc2 + acc3);
    v += __shfl_xor(v, 16);
    v += __shfl_xor(v, 32);
    if (lane < 16) partials[btl][dg][lane] = v;
    __syncthreads();

    if (tid < 32) {
        const int bt = tid >> 4, b = tid & 15;
        const int bo = bq + 16 * bt + b;
        if (bo < nB)
            out[bo] = partials[bt][0][b] + partials[bt][1][b]
                    + partials[bt][2][b] + partials[bt][3][b] + fc_b[0];
    }
}

extern "C" void kernel_launch(void* const* d_in, const int* in_sizes, int n_in,
                              void* d_out, int out_size, void* d_ws, size_t ws_size,
                              hipStream_t stream) {
    const float* entity_emb   = (const float*)d_in[0];
    const float* relation_emb = (const float*)d_in[1];
    const float* conv_w       = (const float*)d_in[2];
    const float* conv_b       = (const float*)d_in[3];
    const float* fc_w         = (const float*)d_in[4];
    const float* fc_b         = (const float*)d_in[5];
    const int*   batch_inputs = (const int*)d_in[6];
    float* out = (float*)d_out;

    const int nB = in_sizes[6] / 3;          // 16384
    const int blocks = (nB + 31) / 32;       // 512
    grcnet_mfma2<<<blocks, 512, 0, stream>>>(
        entity_emb, relation_emb, conv_w, conv_b, fc_w, fc_b, batch_inputs, out, nB);
}

// Round 17
// 53.324 us; speedup vs baseline: 1.3671x; 1.1591x over previous
//
#include <hip/hip_runtime.h>

// GrCNetConvOnly: out[b] = sum_{c,d} relu(wa[c]*h+wb[c]*r+wc[c]*t+cb[c]) * fcw[c*D+d] + fcb
// B=16384, D=400, C=50.
// R17 = R11 structure + conv-coeffs-in-SGPR, with waves_per_eu(2,4) (NO forced floor).
// Evidence: R12 warm profile shows VALU-bound, VGPR=116 -> 4 waves/SIMD, 35% idle.
// R13 proved readfirstlane conv->SGPR works (SGPR=112) but its (6,8) cap forced a spill;
// R14 confounded with a saddr rewrite. This round isolates the SGPR move: natural VGPR
// demand ~116-52 => ~70 -> runtime occupancy 6 waves/SIMD (LDS 43KB = 3 blocks/CU cap).
// MFMA path abandoned: K=4/32 stage-1 + matrix-vector stage-2 waste makes its best case
// equal the VALU floor (R15 72.9, R16 61.8 vs R11 44.9).

typedef _Float16 h2 __attribute__((ext_vector_type(2)));
typedef _Float16 h8 __attribute__((ext_vector_type(8)));

constexpr int D    = 400;
constexpr int CP   = 25;     // real channel pairs
constexpr int DPAD = 404;    // 4 zeroed pad entries per row: inactive lanes read 0

static __device__ __forceinline__ float dot2acc(h2 a, h2 b, float c) {
#if __has_builtin(__builtin_amdgcn_fdot2)
    return __builtin_amdgcn_fdot2(a, b, c, false);
#else
    h2 p = a * b; return c + (float)p[0] + (float)p[1];
#endif
}
static __device__ __forceinline__ h2 dup(float v) {
    _Float16 x = (_Float16)v; h2 r; r[0] = x; r[1] = x; return r;
}
static __device__ __forceinline__ h2 s2h(unsigned u) {
    return __builtin_bit_cast(h2, u);
}

__global__ __attribute__((amdgpu_flat_work_group_size(512, 512), amdgpu_waves_per_eu(2, 4)))
void grcnet_pk16k(
    const float* __restrict__ entity_emb,
    const float* __restrict__ relation_emb,
    const float* __restrict__ conv_w,       // (C,1,1,3)
    const float* __restrict__ conv_b,       // (C)
    const float* __restrict__ fc_w,         // (C*D) c-major
    const float* __restrict__ fc_b,         // (1)
    const int*   __restrict__ batch_inputs, // (B,3)
    float* __restrict__ out,                // (B)
    int nB)
{
    __shared__ h2    fc_lds[CP + 1][DPAD];  // 42016 B; row 25 = zeros (dummy cp)
    __shared__ h2    conv_lds[CP + 1][4];   // row 25 mirrors row 24 (harmless)
    __shared__ float partials[2][2][4][4];  // [g][hc][grp][b]

    const int tid  = threadIdx.x;
    const int lane = tid & 63;
    const int wv   = tid >> 6;              // 0..7
    const int grp  = wv >> 1;               // b-group 0..3
    const int hc   = wv & 1;                // cp-half 0..1
    const int bq   = blockIdx.x * 32;       // 32 b per block
    if (bq >= nB) return;

    // per-lane row pointers (R11-proven; saddr rewrite of R14 deliberately NOT used)
    const float *p0h, *p0r, *p0t, *p1h, *p1r, *p1t;
    const float *p2h, *p2r, *p2t, *p3h, *p3r, *p3t;

    #define SETPTRS(B0)                                                           \
    {                                                                             \
        const int bbase = __builtin_amdgcn_readfirstlane((B0) + 4 * grp);         \
        const int* bi = batch_inputs + 3 * bbase;                                 \
        p0h = entity_emb   + (size_t)bi[0]  * D + lane;                           \
        p0r = relation_emb + (size_t)bi[1]  * D + lane;                           \
        p0t = entity_emb   + (size_t)bi[2]  * D + lane;                           \
        p1h = entity_emb   + (size_t)bi[3]  * D + lane;                           \
        p1r = relation_emb + (size_t)bi[4]  * D + lane;                           \
        p1t = entity_emb   + (size_t)bi[5]  * D + lane;                           \
        p2h = entity_emb   + (size_t)bi[6]  * D + lane;                           \
        p2r = relation_emb + (size_t)bi[7]  * D + lane;                           \
        p2t = entity_emb   + (size_t)bi[8]  * D + lane;                           \
        p3h = entity_emb   + (size_t)bi[9]  * D + lane;                           \
        p3r = relation_emb + (size_t)bi[10] * D + lane;                           \
        p3t = entity_emb   + (size_t)bi[11] * D + lane;                           \
    }

    #define LOADI(S, IDX)                                                         \
        f##S##_0h = p0h[IDX]; f##S##_0r = p0r[IDX]; f##S##_0t = p0t[IDX];         \
        f##S##_1h = p1h[IDX]; f##S##_1r = p1r[IDX]; f##S##_1t = p1t[IDX];         \
        f##S##_2h = p2h[IDX]; f##S##_2r = p2r[IDX]; f##S##_2t = p2t[IDX];         \
        f##S##_3h = p3h[IDX]; f##S##_3r = p3r[IDX]; f##S##_3t = p3t[IDX];

    float fA_0h, fA_0r, fA_0t, fA_1h, fA_1r, fA_1t;
    float fA_2h, fA_2r, fA_2t, fA_3h, fA_3r, fA_3t;
    float fB_0h, fB_0r, fB_0t, fB_1h, fB_1r, fB_1t;
    float fB_2h, fB_2r, fB_2t, fB_3h, fB_3r, fB_3t;

    const h2 zero2 = (h2)(_Float16)0;

    // ---- stage fc_w: float4 x2 -> one b128 ds_write ----
    for (int k = tid; k < CP * 100; k += 512) {
        const int cp = k / 100;
        const int dq = k - cp * 100;
        const float4 A  = *(const float4*)(fc_w + (2*cp)     * D + 4*dq);
        const float4 Bv = *(const float4*)(fc_w + (2*cp + 1) * D + 4*dq);
        h8 g;
        g[0]=(_Float16)A.x; g[1]=(_Float16)Bv.x;
        g[2]=(_Float16)A.y; g[3]=(_Float16)Bv.y;
        g[4]=(_Float16)A.z; g[5]=(_Float16)Bv.z;
        g[6]=(_Float16)A.w; g[7]=(_Float16)Bv.w;
        *(h8*)&fc_lds[cp][4*dq] = g;
    }
    {
        h2 z; z[0] = (_Float16)0; z[1] = (_Float16)0;
        if (tid < CP * 4) fc_lds[tid >> 2][D + (tid & 3)] = z;      // pad d=400..403
        if (tid >= 64 && tid < 64 + DPAD) fc_lds[CP][tid - 64] = z; // dummy row = 0
    }
    if (tid < CP + 1) {
        const int src = (tid == CP) ? (CP - 1) : tid;
        const int c0 = 2 * src;
        h2 wa, wb, wc, cb;
        wa[0]=(_Float16)conv_w[3*c0+0]; wa[1]=(_Float16)conv_w[3*c0+3];
        wb[0]=(_Float16)conv_w[3*c0+1]; wb[1]=(_Float16)conv_w[3*c0+4];
        wc[0]=(_Float16)conv_w[3*c0+2]; wc[1]=(_Float16)conv_w[3*c0+5];
        cb[0]=(_Float16)conv_b[c0];     cb[1]=(_Float16)conv_b[c0+1];
        conv_lds[tid][0]=wa; conv_lds[tid][1]=wb;
        conv_lds[tid][2]=wc; conv_lds[tid][3]=cb;
    }
    __syncthreads();

    // ---- unified c-range: hc=0 -> cps 0..12; hc=1 -> cps 13..24 + dummy ----
    const int C0 = 13 * hc;
    constexpr int NC = 13;

    // conv coefficients -> SGPRs (wave-uniform; frees ~52 VGPRs; R13-proven move)
    unsigned cwa_u[NC], cwb_u[NC], cwc_u[NC], ccb_u[NC];
    #pragma unroll
    for (int j = 0; j < NC; ++j) {
        cwa_u[j] = __builtin_amdgcn_readfirstlane(__builtin_bit_cast(unsigned, conv_lds[C0+j][0]));
        cwb_u[j] = __builtin_amdgcn_readfirstlane(__builtin_bit_cast(unsigned, conv_lds[C0+j][1]));
        cwc_u[j] = __builtin_amdgcn_readfirstlane(__builtin_bit_cast(unsigned, conv_lds[C0+j][2]));
        ccb_u[j] = __builtin_amdgcn_readfirstlane(__builtin_bit_cast(unsigned, conv_lds[C0+j][3]));
    }

    const int  d6 = lane + 384;
    const bool a6 = (d6 < D);
    const int  i6 = a6 ? 384 : -lane;        // p[i6] == row[clamped d]
    const h2* fcb  = &fc_lds[0][0] + C0 * DPAD + lane;
    const h2* fcb6 = &fc_lds[0][0] + C0 * DPAD + (a6 ? d6 : D);

    #define COMPUTE(S, FB, FIDX0)                                                 \
    {                                                                             \
        const h2 H0=dup(f##S##_0h), R0=dup(f##S##_0r), T0=dup(f##S##_0t);         \
        const h2 H1=dup(f##S##_1h), R1=dup(f##S##_1r), T1=dup(f##S##_1t);         \
        const h2 H2=dup(f##S##_2h), R2=dup(f##S##_2r), T2=dup(f##S##_2t);         \
        const h2 H3=dup(f##S##_3h), R3=dup(f##S##_3r), T3=dup(f##S##_3t);         \
        _Pragma("unroll")                                                         \
        for (int j = 0; j < NC; ++j) {                                            \
            const h2 wa = s2h(cwa_u[j]), wb = s2h(cwb_u[j]);                      \
            const h2 wc = s2h(cwc_u[j]), cb = s2h(ccb_u[j]);                      \
            const h2 f2 = (FB)[(FIDX0) + j * DPAD];      /* imm offset */         \
            h2 s0 = H0*wa + (R0*wb + (T0*wc + cb));                               \
            h2 s1 = H1*wa + (R1*wb + (T1*wc + cb));                               \
            h2 s2 = H2*wa + (R2*wb + (T2*wc + cb));                               \
            h2 s3 = H3*wa + (R3*wb + (T3*wc + cb));                               \
            s0 = __builtin_elementwise_max(s0, zero2);                            \
            s1 = __builtin_elementwise_max(s1, zero2);                            \
            s2 = __builtin_elementwise_max(s2, zero2);                            \
            s3 = __builtin_elementwise_max(s3, zero2);                            \
            acc0 = dot2acc(s0, f2, acc0);                                         \
            acc1 = dot2acc(s1, f2, acc1);                                         \
            acc2 = dot2acc(s2, f2, acc2);                                         \
            acc3 = dot2acc(s3, f2, acc3);                                         \
        }                                                                         \
    }

    #pragma unroll 1
    for (int g = 0; g < 2; ++g) {
        const int b0 = bq + 16 * g;
        SETPTRS(b0)
        LOADI(A, 0)
        LOADI(B, 64)
        float acc0 = 0.f, acc1 = 0.f, acc2 = 0.f, acc3 = 0.f;

        COMPUTE(A, fcb, 0*64)   LOADI(A, 128)
        COMPUTE(B, fcb, 1*64)   LOADI(B, 192)
        COMPUTE(A, fcb, 2*64)   LOADI(A, 256)
        COMPUTE(B, fcb, 3*64)   LOADI(B, 320)
        COMPUTE(A, fcb, 4*64)   LOADI(A, i6)
        COMPUTE(B, fcb, 5*64)
        COMPUTE(A, fcb6, 0)

        #pragma unroll
        for (int off = 32; off > 0; off >>= 1) {
            acc0 += __shfl_xor(acc0, off);
            acc1 += __shfl_xor(acc1, off);
            acc2 += __shfl_xor(acc2, off);
            acc3 += __shfl_xor(acc3, off);
        }
        if (lane == 0) {
            partials[g][hc][grp][0] = acc0; partials[g][hc][grp][1] = acc1;
            partials[g][hc][grp][2] = acc2; partials[g][hc][grp][3] = acc3;
        }
    }
    #undef COMPUTE
    #undef LOADI
    #undef SETPTRS

    __syncthreads();

    if (tid < 32) {
        const int g = tid >> 4, idx = tid & 15;
        const int gr = idx >> 2, j = idx & 3;
        const int b = bq + 16 * g + 4 * gr + j;
        if (b < nB)
            out[b] = partials[g][0][gr][j] + partials[g][1][gr][j] + fc_b[0];
    }
}

extern "C" void kernel_launch(void* const* d_in, const int* in_sizes, int n_in,
                              void* d_out, int out_size, void* d_ws, size_t ws_size,
                              hipStream_t stream) {
    const float* entity_emb   = (const float*)d_in[0];
    const float* relation_emb = (const float*)d_in[1];
    const float* conv_w       = (const float*)d_in[2];
    const float* conv_b       = (const float*)d_in[3];
    const float* fc_w         = (const float*)d_in[4];
    const float* fc_b         = (const float*)d_in[5];
    const int*   batch_inputs = (const int*)d_in[6];
    float* out = (float*)d_out;

    const int nB = in_sizes[6] / 3;          // 16384
    const int blocks = (nB + 31) / 32;       // 512
    grcnet_pk16k<<<blocks, 512, 0, stream>>>(
        entity_emb, relation_emb, conv_w, conv_b, fc_w, fc_b, batch_inputs, out, nB);
}

// Round 18
// 46.884 us; speedup vs baseline: 1.5549x; 1.1374x over previous
//
#include <hip/hip_runtime.h>

// GrCNetConvOnly: out[b] = sum_{c,d} relu(wa[c]*h+wb[c]*r+wc[c]*t+cb[c]) * fcw[c*D+d] + fcb
// B=16384, D=400, C=50.
// R18 = clean R11 (best measured: 44.9us; warm profile 43.2us/rep in R12 form).
// Final structure after 17 rounds:
//  - packed-f16 along c (v_pk_fma_f16) + f32 accumulate via v_dot2_f32_f16
//  - 512-thr blocks, 32 b's each: 4 b-groups x 2 cp-halves (unified path, dummy cp row)
//  - fc_w staged once to LDS as h2 [cp][d] (+4-entry zero pad -> maskless d-edge),
//    per-read address = base + compile-time immediate, conflict-free
//  - conv coeffs hoisted to VGPRs (SGPR variants all regressed: R13/R14/R17)
//  - 2-deep A/B load pipeline (3-deep flat: R10; d-blocking worse: R9)
// Closed dead ends: fp16-everything spills (R3/R6), forced waves_per_eu caps spill
// (R13), MFMA hybrid loses at K=4/32 + matrix-vector waste (R15/R16).
// Measured equilibrium: VALU-bound, VALUBusy ~65%, 4 waves/SIMD, memory fully hidden.

typedef _Float16 h2 __attribute__((ext_vector_type(2)));
typedef _Float16 h8 __attribute__((ext_vector_type(8)));

constexpr int D    = 400;
constexpr int CP   = 25;     // real channel pairs
constexpr int DPAD = 404;    // 4 zeroed pad entries per row: inactive lanes read 0

static __device__ __forceinline__ float dot2acc(h2 a, h2 b, float c) {
#if __has_builtin(__builtin_amdgcn_fdot2)
    return __builtin_amdgcn_fdot2(a, b, c, false);
#else
    h2 p = a * b; return c + (float)p[0] + (float)p[1];
#endif
}
static __device__ __forceinline__ h2 dup(float v) {
    _Float16 x = (_Float16)v; h2 r; r[0] = x; r[1] = x; return r;
}

__global__ __attribute__((amdgpu_flat_work_group_size(512, 512), amdgpu_waves_per_eu(2, 4)))
void grcnet_pk16final(
    const float* __restrict__ entity_emb,
    const float* __restrict__ relation_emb,
    const float* __restrict__ conv_w,       // (C,1,1,3)
    const float* __restrict__ conv_b,       // (C)
    const float* __restrict__ fc_w,         // (C*D) c-major
    const float* __restrict__ fc_b,         // (1)
    const int*   __restrict__ batch_inputs, // (B,3)
    float* __restrict__ out,                // (B)
    int nB)
{
    __shared__ h2    fc_lds[CP + 1][DPAD];  // 42016 B; row 25 = zeros (dummy cp)
    __shared__ h2    conv_lds[CP + 1][4];   // row 25 mirrors row 24 (harmless)
    __shared__ float partials[2][2][4][4];  // [g][hc][grp][b]

    const int tid  = threadIdx.x;
    const int lane = tid & 63;
    const int wv   = tid >> 6;              // 0..7
    const int grp  = wv >> 1;               // b-group 0..3
    const int hc   = wv & 1;                // cp-half 0..1
    const int bq   = blockIdx.x * 32;       // 32 b per block
    if (bq >= nB) return;

    const float *p0h, *p0r, *p0t, *p1h, *p1r, *p1t;
    const float *p2h, *p2r, *p2t, *p3h, *p3r, *p3t;

    #define SETPTRS(B0)                                                           \
    {                                                                             \
        const int bbase = __builtin_amdgcn_readfirstlane((B0) + 4 * grp);         \
        const int* bi = batch_inputs + 3 * bbase;                                 \
        p0h = entity_emb   + (size_t)bi[0]  * D + lane;                           \
        p0r = relation_emb + (size_t)bi[1]  * D + lane;                           \
        p0t = entity_emb   + (size_t)bi[2]  * D + lane;                           \
        p1h = entity_emb   + (size_t)bi[3]  * D + lane;                           \
        p1r = relation_emb + (size_t)bi[4]  * D + lane;                           \
        p1t = entity_emb   + (size_t)bi[5]  * D + lane;                           \
        p2h = entity_emb   + (size_t)bi[6]  * D + lane;                           \
        p2r = relation_emb + (size_t)bi[7]  * D + lane;                           \
        p2t = entity_emb   + (size_t)bi[8]  * D + lane;                           \
        p3h = entity_emb   + (size_t)bi[9]  * D + lane;                           \
        p3r = relation_emb + (size_t)bi[10] * D + lane;                           \
        p3t = entity_emb   + (size_t)bi[11] * D + lane;                           \
    }

    #define LOADI(S, IDX)                                                         \
        f##S##_0h = p0h[IDX]; f##S##_0r = p0r[IDX]; f##S##_0t = p0t[IDX];         \
        f##S##_1h = p1h[IDX]; f##S##_1r = p1r[IDX]; f##S##_1t = p1t[IDX];         \
        f##S##_2h = p2h[IDX]; f##S##_2r = p2r[IDX]; f##S##_2t = p2t[IDX];         \
        f##S##_3h = p3h[IDX]; f##S##_3r = p3r[IDX]; f##S##_3t = p3t[IDX];

    float fA_0h, fA_0r, fA_0t, fA_1h, fA_1r, fA_1t;
    float fA_2h, fA_2r, fA_2t, fA_3h, fA_3r, fA_3t;
    float fB_0h, fB_0r, fB_0t, fB_1h, fB_1r, fB_1t;
    float fB_2h, fB_2r, fB_2t, fB_3h, fB_3r, fB_3t;

    const h2 zero2 = (h2)(_Float16)0;

    // ---- stage fc_w: float4 x2 -> one b128 ds_write ----
    for (int k = tid; k < CP * 100; k += 512) {
        const int cp = k / 100;
        const int dq = k - cp * 100;
        const float4 A  = *(const float4*)(fc_w + (2*cp)     * D + 4*dq);
        const float4 Bv = *(const float4*)(fc_w + (2*cp + 1) * D + 4*dq);
        h8 g;
        g[0]=(_Float16)A.x; g[1]=(_Float16)Bv.x;
        g[2]=(_Float16)A.y; g[3]=(_Float16)Bv.y;
        g[4]=(_Float16)A.z; g[5]=(_Float16)Bv.z;
        g[6]=(_Float16)A.w; g[7]=(_Float16)Bv.w;
        *(h8*)&fc_lds[cp][4*dq] = g;
    }
    {
        h2 z; z[0] = (_Float16)0; z[1] = (_Float16)0;
        if (tid < CP * 4) fc_lds[tid >> 2][D + (tid & 3)] = z;      // pad d=400..403
        if (tid >= 64 && tid < 64 + DPAD) fc_lds[CP][tid - 64] = z; // dummy row = 0
    }
    if (tid < CP + 1) {
        const int src = (tid == CP) ? (CP - 1) : tid;
        const int c0 = 2 * src;
        h2 wa, wb, wc, cb;
        wa[0]=(_Float16)conv_w[3*c0+0]; wa[1]=(_Float16)conv_w[3*c0+3];
        wb[0]=(_Float16)conv_w[3*c0+1]; wb[1]=(_Float16)conv_w[3*c0+4];
        wc[0]=(_Float16)conv_w[3*c0+2]; wc[1]=(_Float16)conv_w[3*c0+5];
        cb[0]=(_Float16)conv_b[c0];     cb[1]=(_Float16)conv_b[c0+1];
        conv_lds[tid][0]=wa; conv_lds[tid][1]=wb;
        conv_lds[tid][2]=wc; conv_lds[tid][3]=cb;
    }
    __syncthreads();

    // ---- unified c-range: hc=0 -> cps 0..12; hc=1 -> cps 13..24 + dummy ----
    const int C0 = 13 * hc;
    constexpr int NC = 13;
    h2 cwa[NC], cwb[NC], cwc[NC], ccb[NC];
    #pragma unroll
    for (int j = 0; j < NC; ++j) {
        cwa[j] = conv_lds[C0+j][0]; cwb[j] = conv_lds[C0+j][1];
        cwc[j] = conv_lds[C0+j][2]; ccb[j] = conv_lds[C0+j][3];
    }

    const int  d6 = lane + 384;
    const bool a6 = (d6 < D);
    const int  i6 = a6 ? 384 : -lane;        // p[i6] == row[clamped d]
    const h2* fcb  = &fc_lds[0][0] + C0 * DPAD + lane;
    const h2* fcb6 = &fc_lds[0][0] + C0 * DPAD + (a6 ? d6 : D);

    #define COMPUTE(S, FB, FIDX0)                                                 \
    {                                                                             \
        const h2 H0=dup(f##S##_0h), R0=dup(f##S##_0r), T0=dup(f##S##_0t);         \
        const h2 H1=dup(f##S##_1h), R1=dup(f##S##_1r), T1=dup(f##S##_1t);         \
        const h2 H2=dup(f##S##_2h), R2=dup(f##S##_2r), T2=dup(f##S##_2t);         \
        const h2 H3=dup(f##S##_3h), R3=dup(f##S##_3r), T3=dup(f##S##_3t);         \
        _Pragma("unroll")                                                         \
        for (int j = 0; j < NC; ++j) {                                            \
            const h2 f2 = (FB)[(FIDX0) + j * DPAD];      /* imm offset */         \
            h2 s0 = H0*cwa[j] + (R0*cwb[j] + (T0*cwc[j] + ccb[j]));               \
            h2 s1 = H1*cwa[j] + (R1*cwb[j] + (T1*cwc[j] + ccb[j]));               \
            h2 s2 = H2*cwa[j] + (R2*cwb[j] + (T2*cwc[j] + ccb[j]));               \
            h2 s3 = H3*cwa[j] + (R3*cwb[j] + (T3*cwc[j] + ccb[j]));               \
            s0 = __builtin_elementwise_max(s0, zero2);                            \
            s1 = __builtin_elementwise_max(s1, zero2);                            \
            s2 = __builtin_elementwise_max(s2, zero2);                            \
            s3 = __builtin_elementwise_max(s3, zero2);                            \
            acc0 = dot2acc(s0, f2, acc0);                                         \
            acc1 = dot2acc(s1, f2, acc1);                                         \
            acc2 = dot2acc(s2, f2, acc2);                                         \
            acc3 = dot2acc(s3, f2, acc3);                                         \
        }                                                                         \
    }

    #pragma unroll 1
    for (int g = 0; g < 2; ++g) {
        const int b0 = bq + 16 * g;
        SETPTRS(b0)
        LOADI(A, 0)
        LOADI(B, 64)
        float acc0 = 0.f, acc1 = 0.f, acc2 = 0.f, acc3 = 0.f;

        COMPUTE(A, fcb, 0*64)   LOADI(A, 128)
        COMPUTE(B, fcb, 1*64)   LOADI(B, 192)
        COMPUTE(A, fcb, 2*64)   LOADI(A, 256)
        COMPUTE(B, fcb, 3*64)   LOADI(B, 320)
        COMPUTE(A, fcb, 4*64)   LOADI(A, i6)
        COMPUTE(B, fcb, 5*64)
        COMPUTE(A, fcb6, 0)

        #pragma unroll
        for (int off = 32; off > 0; off >>= 1) {
            acc0 += __shfl_xor(acc0, off);
            acc1 += __shfl_xor(acc1, off);
            acc2 += __shfl_xor(acc2, off);
            acc3 += __shfl_xor(acc3, off);
        }
        if (lane == 0) {
            partials[g][hc][grp][0] = acc0; partials[g][hc][grp][1] = acc1;
            partials[g][hc][grp][2] = acc2; partials[g][hc][grp][3] = acc3;
        }
    }
    #undef COMPUTE
    #undef LOADI
    #undef SETPTRS

    __syncthreads();

    if (tid < 32) {
        const int g = tid >> 4, idx = tid & 15;
        const int gr = idx >> 2, j = idx & 3;
        const int b = bq + 16 * g + 4 * gr + j;
        if (b < nB)
            out[b] = partials[g][0][gr][j] + partials[g][1][gr][j] + fc_b[0];
    }
}

extern "C" void kernel_launch(void* const* d_in, const int* in_sizes, int n_in,
                              void* d_out, int out_size, void* d_ws, size_t ws_size,
                              hipStream_t stream) {
    const float* entity_emb   = (const float*)d_in[0];
    const float* relation_emb = (const float*)d_in[1];
    const float* conv_w       = (const float*)d_in[2];
    const float* conv_b       = (const float*)d_in[3];
    const float* fc_w         = (const float*)d_in[4];
    const float* fc_b         = (const float*)d_in[5];
    const int*   batch_inputs = (const int*)d_in[6];
    float* out = (float*)d_out;

    const int nB = in_sizes[6] / 3;          // 16384
    const int blocks = (nB + 31) / 32;       // 512
    grcnet_pk16final<<<blocks, 512, 0, stream>>>(
        entity_emb, relation_emb, conv_w, conv_b, fc_w, fc_b, batch_inputs, out, nB);
}